// Round 1
// baseline (589.753 us; speedup 1.0000x reference)
//
#include <hip/hip_runtime.h>
#include <hip/hip_bf16.h>
#include <math.h>

#define T_ 4096
#define H_ 1024
#define E_ 8
#define I_ 2048
#define EPS_ 1e-5f

using bf16x8 = __attribute__((ext_vector_type(8))) short;
using f32x4  = __attribute__((ext_vector_type(4))) float;

static __device__ __forceinline__ unsigned short f2bf(float f) {
    union { float f; unsigned int u; } v; v.f = f;
    unsigned int u = v.u;
    u += 0x7fffu + ((u >> 16) & 1u);   // RNE
    return (unsigned short)(u >> 16);
}

// async global->LDS, 16B per lane; LDS dest must be wave-uniform base (+lane*16 by HW)
static __device__ __forceinline__ void gld16(const unsigned short* g, unsigned short* l) {
    __builtin_amdgcn_global_load_lds(
        (const __attribute__((address_space(1))) unsigned int*)g,
        (__attribute__((address_space(3))) unsigned int*)l,
        16, 0, 0);
}

// ---------------- Kernel 0: fp32 -> bf16 weight preconvert -----------------
__global__ __launch_bounds__(256) void k_convert(
    const float* __restrict__ src, unsigned short* __restrict__ dst)
{
    size_t i = (size_t)blockIdx.x * 256 + threadIdx.x;
    const float4* s = (const float4*)src + i * 2;
    float4 a = s[0], b = s[1];
    ushort4 lo, hi;
    lo.x = f2bf(a.x); lo.y = f2bf(a.y); lo.z = f2bf(a.z); lo.w = f2bf(a.w);
    hi.x = f2bf(b.x); hi.y = f2bf(b.y); hi.z = f2bf(b.z); hi.w = f2bf(b.w);
    ((ushort4*)dst)[i * 2]     = lo;
    ((ushort4*)dst)[i * 2 + 1] = hi;
}

// ---------------- Kernel 1: RMSNorm + gating, one wave per token -----------
__global__ __launch_bounds__(256) void k_norm_gate(
    const float* __restrict__ x, const float* __restrict__ scale,
    const float* __restrict__ gk, const float* __restrict__ gb,
    unsigned short* __restrict__ normed_bf,
    int* __restrict__ counts, int* __restrict__ tok_list, float* __restrict__ wtok)
{
    int tid = threadIdx.x;
    int wave = tid >> 6, lane = tid & 63;
    int t = blockIdx.x * 4 + wave;
    const float* xr = x + (size_t)t * H_;
    int h0 = lane * 16;

    float4 xv[4], sv[4];
    #pragma unroll
    for (int c = 0; c < 4; c++) {
        xv[c] = *(const float4*)(xr + h0 + c * 4);
        sv[c] = *(const float4*)(scale + h0 + c * 4);
    }
    float ss = 0.f;
    #pragma unroll
    for (int c = 0; c < 4; c++)
        ss += xv[c].x*xv[c].x + xv[c].y*xv[c].y + xv[c].z*xv[c].z + xv[c].w*xv[c].w;
    #pragma unroll
    for (int off = 32; off; off >>= 1) ss += __shfl_xor(ss, off);
    float inv = 1.0f / sqrtf(ss / (float)H_ + EPS_);

    float nv[16];
    #pragma unroll
    for (int c = 0; c < 4; c++) {
        nv[c*4+0] = xv[c].x * inv * sv[c].x;
        nv[c*4+1] = xv[c].y * inv * sv[c].y;
        nv[c*4+2] = xv[c].z * inv * sv[c].z;
        nv[c*4+3] = xv[c].w * inv * sv[c].w;
    }
    #pragma unroll
    for (int c = 0; c < 4; c++) {
        ushort4 nb;
        nb.x = f2bf(nv[c*4+0]); nb.y = f2bf(nv[c*4+1]);
        nb.z = f2bf(nv[c*4+2]); nb.w = f2bf(nv[c*4+3]);
        *(ushort4*)(normed_bf + (size_t)t * H_ + h0 + c * 4) = nb;
    }

    float p[E_];
    #pragma unroll
    for (int e = 0; e < E_; e++) p[e] = 0.f;
    #pragma unroll
    for (int j = 0; j < 16; j++) {
        const float4* g4 = (const float4*)(gk + (size_t)(h0 + j) * E_);
        float4 a = g4[0], b = g4[1];
        float n = nv[j];
        p[0] += n*a.x; p[1] += n*a.y; p[2] += n*a.z; p[3] += n*a.w;
        p[4] += n*b.x; p[5] += n*b.y; p[6] += n*b.z; p[7] += n*b.w;
    }
    #pragma unroll
    for (int e = 0; e < E_; e++) {
        #pragma unroll
        for (int off = 32; off; off >>= 1) p[e] += __shfl_xor(p[e], off);
    }
    if (lane == 0) {
        int b0 = -1, b1 = -1; float l0 = -1e30f, l1 = -1e30f;
        #pragma unroll
        for (int e = 0; e < E_; e++) {
            float lg = p[e] + gb[e];
            if (lg > l0) { l1 = l0; b1 = b0; l0 = lg; b0 = e; }
            else if (lg > l1) { l1 = lg; b1 = e; }
        }
        float e1 = expf(l1 - l0);
        float w0 = 1.f / (1.f + e1);
        float w1 = e1 / (1.f + e1);
        wtok[t * 2 + 0] = w0;
        wtok[t * 2 + 1] = w1;
        int p0 = atomicAdd(&counts[b0], 1);
        tok_list[b0 * T_ + p0] = t * 2 + 0;
        int p1 = atomicAdd(&counts[b1], 1);
        tok_list[b1 * T_ + p1] = t * 2 + 1;
    }
}

// ---------------- Kernel 3: GEMM1, 128 tok x 64 I-cols (gate+linear) -------
// m97 structure: global_load_lds width=16, linear LDS dest, source-swizzled.
// LDS row = 64 bf16 (128 B); logical 16B-chunk j of row r lives at physical
// chunk j^(r&7). gld writes linearly -> lane loads global chunk p^(r&7).
__global__ __launch_bounds__(256) void k_mlp1(
    const unsigned short* __restrict__ w1b,
    const float* __restrict__ b1,
    const unsigned short* __restrict__ normed_bf,
    const int* __restrict__ counts, const int* __restrict__ tok_list,
    unsigned short* __restrict__ act)
{
    int e = blockIdx.z;
    int Ne = counts[e];
    int mt0 = blockIdx.y * 128;
    if (mt0 >= Ne) return;
    int it0 = blockIdx.x * 64;
    int tid = threadIdx.x;
    int lane = tid & 63, w = tid >> 6;
    int quad = lane >> 4, m16 = lane & 15;
    int wr = w >> 1, wc = w & 1;

    __shared__ unsigned short lA[128 * 64];
    __shared__ unsigned short lBg[64 * 64];
    __shared__ unsigned short lBl[64 * 64];
    __shared__ int ls_tk[128];

    if (tid < 128) {
        int slot = mt0 + tid;
        ls_tk[tid] = (slot < Ne) ? tok_list[e * T_ + slot] : -1;
    }

    int lr = lane >> 3;          // row within 8-row group covered by one gld
    int pc = lane & 7;           // physical 16B chunk this lane fills

    // A: 128 rows, 4 gld/wave (8 rows each)
    const unsigned short* srcA[4];
    #pragma unroll
    for (int it = 0; it < 4; it++) {
        int r = w * 32 + it * 8 + lr;
        int slot = mt0 + r;
        int tk = (slot < Ne) ? tok_list[e * T_ + slot] : 0;
        srcA[it] = normed_bf + (size_t)(tk >> 1) * H_ + ((pc ^ (r & 7)) << 3);
    }
    // B gate/linear: 64 rows each, 2 gld/wave each
    const size_t w1base = (size_t)e * 2 * I_ * H_;
    const unsigned short* srcG[2];
    const unsigned short* srcL[2];
    #pragma unroll
    for (int it = 0; it < 2; it++) {
        int r = w * 16 + it * 8 + lr;
        srcG[it] = w1b + w1base + (size_t)(it0 + r) * H_ + ((pc ^ (r & 7)) << 3);
        srcL[it] = srcG[it] + (size_t)I_ * H_;
    }

    f32x4 accg[4][2], accl[4][2];
    #pragma unroll
    for (int mi = 0; mi < 4; mi++)
        #pragma unroll
        for (int ni = 0; ni < 2; ni++) {
            accg[mi][ni] = (f32x4){0.f, 0.f, 0.f, 0.f};
            accl[mi][ni] = (f32x4){0.f, 0.f, 0.f, 0.f};
        }

    for (int kk = 0; kk < H_; kk += 64) {
        __syncthreads();
        #pragma unroll
        for (int it = 0; it < 4; it++)
            gld16(srcA[it] + kk, &lA[(w * 32 + it * 8) * 64]);
        #pragma unroll
        for (int it = 0; it < 2; it++) {
            gld16(srcG[it] + kk, &lBg[(w * 16 + it * 8) * 64]);
            gld16(srcL[it] + kk, &lBl[(w * 16 + it * 8) * 64]);
        }
        __syncthreads();
        int m7 = m16 & 7;
        #pragma unroll
        for (int ks = 0; ks < 2; ks++) {
            int jj = ks * 4 + quad;
            bf16x8 af[4], bg[2], bl[2];
            #pragma unroll
            for (int mi = 0; mi < 4; mi++)
                af[mi] = *(const bf16x8*)(&lA[(wr * 64 + mi * 16 + m16) * 64 + ((jj ^ m7) << 3)]);
            #pragma unroll
            for (int ni = 0; ni < 2; ni++) {
                bg[ni] = *(const bf16x8*)(&lBg[(wc * 32 + ni * 16 + m16) * 64 + ((jj ^ m7) << 3)]);
                bl[ni] = *(const bf16x8*)(&lBl[(wc * 32 + ni * 16 + m16) * 64 + ((jj ^ m7) << 3)]);
            }
            #pragma unroll
            for (int mi = 0; mi < 4; mi++)
                #pragma unroll
                for (int ni = 0; ni < 2; ni++) {
                    accg[mi][ni] = __builtin_amdgcn_mfma_f32_16x16x32_bf16(
                        af[mi], bg[ni], accg[mi][ni], 0, 0, 0);
                    accl[mi][ni] = __builtin_amdgcn_mfma_f32_16x16x32_bf16(
                        af[mi], bl[ni], accl[mi][ni], 0, 0, 0);
                }
        }
    }

    const float* b1g = b1 + (size_t)e * 2 * I_;
    const float* b1l = b1g + I_;
    #pragma unroll
    for (int mi = 0; mi < 4; mi++) {
        #pragma unroll
        for (int reg = 0; reg < 4; reg++) {
            int row = wr * 64 + mi * 16 + quad * 4 + reg;
            int tk = ls_tk[row];
            if (tk < 0) continue;
            #pragma unroll
            for (int ni = 0; ni < 2; ni++) {
                int i = it0 + wc * 32 + ni * 16 + m16;
                float g = accg[mi][ni][reg] + b1g[i];
                float l = accl[mi][ni][reg] + b1l[i];
                g = fminf(g, 7.f);
                l = fminf(fmaxf(l, -7.f), 7.f);
                float sw = g / (1.f + expf(-1.702f * g));
                act[(size_t)tk * I_ + i] = f2bf(sw * (l + 1.f));
            }
        }
    }
}

// ---------------- Kernel 4: GEMM2, 128 tok x 128 H-cols --------------------
__global__ __launch_bounds__(256) void k_mlp2(
    const unsigned short* __restrict__ w2b,
    const float* __restrict__ b2,
    const unsigned short* __restrict__ act,
    const int* __restrict__ counts, const int* __restrict__ tok_list,
    float* __restrict__ ybuf)
{
    int e = blockIdx.z;
    int Ne = counts[e];
    int mt0 = blockIdx.y * 128;
    if (mt0 >= Ne) return;
    int ht0 = blockIdx.x * 128;
    int tid = threadIdx.x;
    int lane = tid & 63, w = tid >> 6;
    int quad = lane >> 4, m16 = lane & 15;
    int wr = w >> 1, wc = w & 1;

    __shared__ unsigned short lA[128 * 64];
    __shared__ unsigned short lB[128 * 64];
    __shared__ int ls_tk[128];

    if (tid < 128) {
        int slot = mt0 + tid;
        ls_tk[tid] = (slot < Ne) ? tok_list[e * T_ + slot] : -1;
    }

    int lr = lane >> 3;
    int pc = lane & 7;

    const unsigned short* srcA[4];
    #pragma unroll
    for (int it = 0; it < 4; it++) {
        int r = w * 32 + it * 8 + lr;
        int slot = mt0 + r;
        int tk = (slot < Ne) ? tok_list[e * T_ + slot] : 0;
        srcA[it] = act + (size_t)tk * I_ + ((pc ^ (r & 7)) << 3);
    }
    const size_t w2base = (size_t)e * H_ * I_;
    const unsigned short* srcB[4];
    #pragma unroll
    for (int it = 0; it < 4; it++) {
        int r = w * 32 + it * 8 + lr;
        srcB[it] = w2b + w2base + (size_t)(ht0 + r) * I_ + ((pc ^ (r & 7)) << 3);
    }

    f32x4 acc[4][4];
    #pragma unroll
    for (int mi = 0; mi < 4; mi++)
        #pragma unroll
        for (int ni = 0; ni < 4; ni++)
            acc[mi][ni] = (f32x4){0.f, 0.f, 0.f, 0.f};

    for (int kk = 0; kk < I_; kk += 64) {
        __syncthreads();
        #pragma unroll
        for (int it = 0; it < 4; it++)
            gld16(srcA[it] + kk, &lA[(w * 32 + it * 8) * 64]);
        #pragma unroll
        for (int it = 0; it < 4; it++)
            gld16(srcB[it] + kk, &lB[(w * 32 + it * 8) * 64]);
        __syncthreads();
        int m7 = m16 & 7;
        #pragma unroll
        for (int ks = 0; ks < 2; ks++) {
            int jj = ks * 4 + quad;
            bf16x8 af[4], bv[4];
            #pragma unroll
            for (int mi = 0; mi < 4; mi++)
                af[mi] = *(const bf16x8*)(&lA[(wr * 64 + mi * 16 + m16) * 64 + ((jj ^ m7) << 3)]);
            #pragma unroll
            for (int ni = 0; ni < 4; ni++)
                bv[ni] = *(const bf16x8*)(&lB[(wc * 64 + ni * 16 + m16) * 64 + ((jj ^ m7) << 3)]);
            #pragma unroll
            for (int mi = 0; mi < 4; mi++)
                #pragma unroll
                for (int ni = 0; ni < 4; ni++)
                    acc[mi][ni] = __builtin_amdgcn_mfma_f32_16x16x32_bf16(
                        af[mi], bv[ni], acc[mi][ni], 0, 0, 0);
        }
    }

    const float* b2e = b2 + (size_t)e * H_;
    #pragma unroll
    for (int mi = 0; mi < 4; mi++) {
        #pragma unroll
        for (int reg = 0; reg < 4; reg++) {
            int row = wr * 64 + mi * 16 + quad * 4 + reg;
            int tk = ls_tk[row];
            if (tk < 0) continue;
            #pragma unroll
            for (int ni = 0; ni < 4; ni++) {
                int h = ht0 + wc * 64 + ni * 16 + m16;
                ybuf[(size_t)tk * H_ + h] = acc[mi][ni][reg] + b2e[h];
            }
        }
    }
}

// ---------------- Kernel 5: out = x + w0*y0 + w1*y1 ------------------------
__global__ __launch_bounds__(256) void k_combine(
    const float* __restrict__ x, const float* __restrict__ ybuf,
    const float* __restrict__ wtok, float* __restrict__ out)
{
    int t = blockIdx.x;
    int tid = threadIdx.x;
    float w0 = wtok[t * 2 + 0];
    float w1 = wtok[t * 2 + 1];
    float4 xv = ((const float4*)(x + (size_t)t * H_))[tid];
    float4 y0 = ((const float4*)(ybuf + (size_t)(t * 2) * H_))[tid];
    float4 y1 = ((const float4*)(ybuf + (size_t)(t * 2 + 1) * H_))[tid];
    float4 o;
    o.x = xv.x + w0 * y0.x + w1 * y1.x;
    o.y = xv.y + w0 * y0.y + w1 * y1.y;
    o.z = xv.z + w0 * y0.z + w1 * y1.z;
    o.w = xv.w + w0 * y0.w + w1 * y1.w;
    ((float4*)(out + (size_t)t * H_))[tid] = o;
}

// ---------------- launcher -------------------------------------------------
extern "C" void kernel_launch(void* const* d_in, const int* in_sizes, int n_in,
                              void* d_out, int out_size, void* d_ws, size_t ws_size,
                              hipStream_t stream) {
    const float* x     = (const float*)d_in[0];
    const float* scale = (const float*)d_in[1];
    const float* gk    = (const float*)d_in[2];
    const float* gb    = (const float*)d_in[3];
    const float* w1    = (const float*)d_in[4];
    const float* b1    = (const float*)d_in[5];
    const float* w2    = (const float*)d_in[6];
    const float* b2    = (const float*)d_in[7];
    float* out = (float*)d_out;

    char* ws = (char*)d_ws;
    const size_t MB = 1024 * 1024;
    unsigned short* normed_bf = (unsigned short*)ws;                  // 8 MB
    unsigned short* act       = (unsigned short*)(ws + 8 * MB);       // 32 MB
    unsigned short* w1b       = (unsigned short*)(ws + 40 * MB);      // 64 MB
    float*          ybuf      = (float*)(ws + 40 * MB);               // 32 MB, aliases w1b (dead after k_mlp1)
    unsigned short* w2b       = (unsigned short*)(ws + 104 * MB);     // 32 MB
    char* ctl                 = ws + 136 * MB;
    int*   counts   = (int*)ctl;                                      // 256 B pad
    int*   tok_list = (int*)(ctl + 256);                              // E*T*4 = 128 KB
    float* wtok     = (float*)(ctl + 256 + (size_t)E_ * T_ * 4);      // 2T*4 = 32 KB

    hipMemsetAsync(counts, 0, E_ * sizeof(int), stream);

    k_norm_gate<<<dim3(T_ / 4), dim3(256), 0, stream>>>(
        x, scale, gk, gb, normed_bf, counts, tok_list, wtok);
    k_convert<<<dim3((E_ * 2 * I_ * H_) / (256 * 8)), dim3(256), 0, stream>>>(w1, w1b);
    k_convert<<<dim3((E_ * H_ * I_) / (256 * 8)), dim3(256), 0, stream>>>(w2, w2b);

    k_mlp1<<<dim3(I_ / 64, T_ / 128, E_), dim3(256), 0, stream>>>(
        w1b, b1, normed_bf, counts, tok_list, act);
    k_mlp2<<<dim3(H_ / 128, T_ / 128, E_), dim3(256), 0, stream>>>(
        w2b, b2, act, counts, tok_list, ybuf);
    k_combine<<<dim3(T_), dim3(256), 0, stream>>>(x, ybuf, wtok, out);
}